// Round 12
// baseline (70.441 us; speedup 1.0000x reference)
//
#include <hip/hip_runtime.h>

// Problem constants (fixed by reference setup_inputs)
constexpr int B = 4, N = 16384, Q = 4096, C = 64, S = 32;
constexpr int TS = 68;              // LDS tile row stride (floats)
constexpr int QBLKS = (B * Q) / 2;  // 8192 scan+gather blocks (2 waves each)

typedef float f32x4 __attribute__((ext_vector_type(4)));

// ---------------------------------------------------------------------------
// Kernel 1: transpose features (B,C,N) -> (B,N,C) into ws. sc0 sc1 stores
// write through to the coherence point (L3) so post-invalidate L2 refills are
// correct (per-XCD L2s aren't cross-coherent; graph replay doesn't re-clean).
// ---------------------------------------------------------------------------
__global__ __launch_bounds__(256) void transpose_feat(const float* __restrict__ f,
                                                      float* __restrict__ ft) {
    __shared__ float tile[64 * 65];
    const int b  = blockIdx.x >> 8;           // N/64 = 256 blocks per batch
    const int n0 = (blockIdx.x & 255) * 64;
    const int t  = threadIdx.x;
    const int nl = t & 63;
    const int cl = t >> 6;
    const float* fb = f + (size_t)b * C * N;
#pragma unroll
    for (int i = 0; i < 16; ++i) {
        const int c = i * 4 + cl;
        tile[c * 65 + nl] = fb[(size_t)c * N + n0 + nl];   // 256B coalesced per c
    }
    __syncthreads();
    float* ftb = ft + ((size_t)b * N + n0) * C;
    const int l15 = t & 15;
    const int nw  = t >> 4;                    // 0..15
#pragma unroll
    for (int it = 0; it < 4; ++it) {
        const int n = it * 16 + nw;
        f32x4 v;
#pragma unroll
        for (int k = 0; k < 4; ++k) v[k] = tile[(4 * l15 + k) * 65 + n];
        float* p = ftb + (size_t)n * C + 4 * l15;
        asm volatile("global_store_dwordx4 %0, %1, off sc0 sc1"
                     :: "v"(p), "v"(v) : "memory");
    }
}

// ---------------------------------------------------------------------------
// Kernel 1.5 "flush": one-time L2 writeback+invalidate on every XCD, while
// nothing else runs. 256 one-wave blocks span all 8 XCDs; each issues a
// device-scope fence (buffer_wbl2 sc1 + buffer_inv sc1 — r3-proven codegen of
// __threadfence). This evicts the harness's one-time 0xAA poison from all
// consumer L2s, so the gather kernel may use PLAIN CACHED loads on ft (8x
// row reuse in L2). r3 lesson: per-block fences in the hot kernel thrash;
// one fence per XCD up-front, with nothing co-resident, is nearly free.
// ---------------------------------------------------------------------------
__global__ __launch_bounds__(64) void l2flush() {
    __threadfence();
}

// ---------------------------------------------------------------------------
// Kernel 2 "sg": fused scan+gather, one wave per query, 2 waves per block,
// per-wave LDS, no __syncthreads. Identical to r10 except the ft gathers are
// now plain cached dwordx4 (L2-served after the flush). vmcnt counting is
// unchanged: compiler-inserted loads only increase the younger-op count,
// making each counted wait stricter, never looser.
// ---------------------------------------------------------------------------
__global__ __launch_bounds__(128, 8) void sg(const float* __restrict__ q_xyz,
                                             const float* __restrict__ s_xyz,
                                             const float* __restrict__ ft,
                                             float* __restrict__ out) {
    __shared__ int   idx_s[2][S];
    __shared__ float tile[2][16 * TS];

    const int t    = threadIdx.x;
    const int lane = t & 63;
    const int wid  = t >> 6;                 // 0..1
    const int gq   = blockIdx.x * 2 + wid;   // 0..B*Q-1
    const int b    = gq >> 12;               // Q = 4096
    const int q    = gq & (Q - 1);

    const float* qp = q_xyz + (size_t)gq * 3;
    const float qxf = qp[0], qyf = qp[1], qzf = qp[2];
    const double qxd = (double)qxf, qyd = (double)qyf, qzd = (double)qzf;
    const double R2D = 0.2 * 0.2;   // IEEE double = python's radius*radius
    const float R2F = 0.04f, EPS = 4e-6f;
    const float* sb = s_xyz + (size_t)b * N * 3;

    // ---- phase 1: ordered ballot ball-query (f32 prefilter, f64 border) ----
    int cnt = 0;                                            // wave-uniform
    float sx = sb[lane * 3 + 0], sy = sb[lane * 3 + 1], sz = sb[lane * 3 + 2];
    for (int base = 0; base < N && cnt < S; base += 64) {
        float nx = sx, ny = sy, nz = sz;
        if (base + 64 < N) {                 // prefetch next chunk
            const int nn = (base + 64 + lane) * 3;
            nx = sb[nn + 0]; ny = sb[nn + 1]; nz = sb[nn + 2];
        }
        const float dxf = sx - qxf, dyf = sy - qyf, dzf = sz - qzf;
        const float d2f = dxf * dxf + dyf * dyf + dzf * dzf;
        bool in = d2f < R2F - EPS;                       // definitely inside
        const bool border = (!in) && (d2f <= R2F + EPS); // needs exact decision
        if (__any(border)) {
            if (border) {
                const double dx = (double)sx - qxd;
                const double dy = (double)sy - qyd;
                const double dz = (double)sz - qzd;
                in = (dx * dx + dy * dy + dz * dz) < R2D;   // exact f64 (proven)
            }
        }
        const unsigned long long m = __ballot(in);
        if (in) {
            const int pos = cnt + __popcll(m & ((1ull << lane) - 1ull));
            if (pos < S) idx_s[wid][pos] = base + lane;
        }
        cnt += __popcll(m);
        sx = nx; sy = ny; sz = nz;
    }
    if (cnt > S) cnt = S;
    const int idx0 = (cnt > 0) ? idx_s[wid][0] : 0;
    if (lane < S && lane >= cnt) idx_s[wid][lane] = idx0;  // pad (same wave)

    // ---- phase 2: gather + write ----
    const int sub = lane >> 4;           // 0..3 : row-within-quad for gather
    const int c15 = lane & 15;
    const int cq  = c15 * 4;             // col start (floats) for gather
    const int a4  = lane & 3;            // s-quad within pass for output
    const int ch  = lane >> 2;           // 0..15 : c within 16-c group for output
    float* out1 = out + (size_t)B * 3 * Q * S;
    const float* ftb = ft + (size_t)b * N * C;

    // issue all 8 gather loads up-front — PLAIN CACHED (L2 reuse ~8x) G0..G7
    f32x4 v[8];
#pragma unroll
    for (int j = 0; j < 8; ++j) {
        const int id = idx_s[wid][j * 4 + sub];
        const float* p = ftb + ((size_t)id << 6) + cq;
        asm volatile("global_load_dwordx4 %0, %1, off"
                     : "=v"(v[j]) : "v"(p));
    }

    // grouped_xyz overlaps gather latency: 2 counted asm stores S0,S1
    {
        const int c0 = lane >> 5, s0 = lane & 31;
        const int id0 = idx_s[wid][s0];
        const float w0 = sb[id0 * 3 + c0] - qp[c0];
        float* p0 = out + (((size_t)b * 3 + c0) * Q + q) * S + s0;
        asm volatile("global_store_dword %0, %1, off" :: "v"(p0), "v"(w0) : "memory");
        float w1 = 0.0f;
        float* p1 = p0;
        if (lane < 32) {
            const int id1 = idx_s[wid][lane];
            w1 = sb[id1 * 3 + 2] - qp[2];
            p1 = out + (((size_t)b * 3 + 2) * Q + q) * S + lane;
        }
        if (lane < 32)
            asm volatile("global_store_dword %0, %1, off" :: "v"(p1), "v"(w1) : "memory");
    }

    // ---- pass 0: s = 0..15 ----
    // >=6 ops younger than G3 (G4..G7,S0,S1) => vmcnt(6) proves G0..G3 done.
    asm volatile("s_waitcnt vmcnt(6)" ::: "memory");
    __builtin_amdgcn_sched_barrier(0);
#pragma unroll
    for (int j = 0; j < 4; ++j) {
        const int r = j * 4 + sub;
        *(f32x4*)&tile[wid][r * TS + cq] = v[j];
    }
#pragma unroll
    for (int i = 0; i < 4; ++i) {        // O0..O3: c = 16i+ch, s quad a4
        const int c = i * 16 + ch;
        f32x4 w;
#pragma unroll
        for (int k = 0; k < 4; ++k)
            w[k] = tile[wid][(4 * a4 + k) * TS + c];
        float* p = out1 + (((size_t)b * C + c) * Q + q) * S + 4 * a4;
        asm volatile("global_store_dwordx4 %0, %1, off" :: "v"(p), "v"(w) : "memory");
    }

    // ---- pass 1: s = 16..31 ----
    // >=4 ops younger than G7 (O0..O3) => vmcnt(4) proves G4..G7 done.
    asm volatile("s_waitcnt vmcnt(4)" ::: "memory");
    __builtin_amdgcn_sched_barrier(0);
#pragma unroll
    for (int j = 0; j < 4; ++j) {
        const int r = j * 4 + sub;
        *(f32x4*)&tile[wid][r * TS + cq] = v[4 + j];
    }
#pragma unroll
    for (int i = 0; i < 4; ++i) {
        const int c = i * 16 + ch;
        f32x4 w;
#pragma unroll
        for (int k = 0; k < 4; ++k)
            w[k] = tile[wid][(4 * a4 + k) * TS + c];
        float* p = out1 + (((size_t)b * C + c) * Q + q) * S + 16 + 4 * a4;
        asm volatile("global_store_dwordx4 %0, %1, off" :: "v"(p), "v"(w) : "memory");
    }
}

// ---------------------------------------------------------------------------
// Fallback (ws too small): fused single kernel, original feature layout.
// ---------------------------------------------------------------------------
__global__ __launch_bounds__(256) void ballgroup_fb(const float* __restrict__ q_xyz,
                                                    const float* __restrict__ s_xyz,
                                                    const float* __restrict__ feat,
                                                    float* __restrict__ out) {
    __shared__ int   idx_s[4][S];
    __shared__ float tile[4][16 * TS];
    const int t = threadIdx.x, lane = t & 63, wid = t >> 6;
    const int gq = blockIdx.x * 4 + wid;
    const int b = gq >> 12, q = gq & (Q - 1);
    const float* qp = q_xyz + (size_t)gq * 3;
    const double qxd = (double)qp[0], qyd = (double)qp[1], qzd = (double)qp[2];
    const double R2D = 0.2 * 0.2;
    const float* sb = s_xyz + (size_t)b * N * 3;
    int cnt = 0;
    for (int base = 0; base < N && cnt < S; base += 64) {
        const int n = base + lane;
        const double dx = (double)sb[n * 3 + 0] - qxd;
        const double dy = (double)sb[n * 3 + 1] - qyd;
        const double dz = (double)sb[n * 3 + 2] - qzd;
        const bool in = (dx * dx + dy * dy + dz * dz) < R2D;
        const unsigned long long m = __ballot(in);
        if (in) {
            const int pos = cnt + __popcll(m & ((1ull << lane) - 1ull));
            if (pos < S) idx_s[wid][pos] = n;
        }
        cnt += __popcll(m);
    }
    if (cnt > S) cnt = S;
    const int idx0 = (cnt > 0) ? idx_s[wid][0] : 0;
    if (lane < S && lane >= cnt) idx_s[wid][lane] = idx0;
    for (int e = lane; e < 3 * S; e += 64) {
        const int c = e >> 5, sI = e & 31;
        const int id = idx_s[wid][sI];
        out[(((size_t)b * 3 + c) * Q + q) * S + sI] = sb[id * 3 + c] - qp[c];
    }
    float* out1 = out + (size_t)B * 3 * Q * S;
    const int chi = lane >> 4, sI16 = lane & 15;
    const float* fb = feat + (size_t)b * C * N;
    for (int p = 0; p < 2; ++p) {
        for (int s2 = 0; s2 < 16; ++s2) {
            const int id = idx_s[wid][p * 16 + s2];
            tile[wid][s2 * TS + lane] = fb[(size_t)lane * N + id];
        }
#pragma unroll
        for (int i = 0; i < 16; ++i) {
            const int c = i * 4 + chi;
            out1[(((size_t)b * C + c) * Q + q) * S + p * 16 + sI16] =
                tile[wid][sI16 * TS + c];
        }
    }
}

extern "C" void kernel_launch(void* const* d_in, const int* in_sizes, int n_in,
                              void* d_out, int out_size, void* d_ws, size_t ws_size,
                              hipStream_t stream) {
    const float* q_xyz = (const float*)d_in[0];   // (B,Q,3)
    const float* s_xyz = (const float*)d_in[1];   // (B,N,3)
    const float* feat  = (const float*)d_in[2];   // (B,C,N)
    float* out = (float*)d_out;

    const size_t ftBytes = (size_t)B * N * C * sizeof(float);   // 16 MB
    if (ws_size >= ftBytes) {
        float* ft = (float*)d_ws;
        transpose_feat<<<B * (N / 64), 256, 0, stream>>>(feat, ft);
        l2flush<<<256, 64, 0, stream>>>();   // one wb+inv per XCD, nothing co-running
        sg<<<QBLKS, 128, 0, stream>>>(q_xyz, s_xyz, ft, out);
    } else {
        ballgroup_fb<<<(B * Q) / 4, 256, 0, stream>>>(q_xyz, s_xyz, feat, out);
    }
}

// Round 13
// 49.131 us; speedup vs baseline: 1.4337x; 1.4337x over previous
//
#include <hip/hip_runtime.h>

// Problem constants (fixed by reference setup_inputs)
constexpr int B = 4, N = 16384, Q = 4096, C = 64, S = 32;
constexpr int TS = 68;              // LDS tile row stride (floats)
constexpr int QBLKS = (B * Q) / 2;  // 8192 scan+gather blocks (2 waves each)

typedef float f32x4 __attribute__((ext_vector_type(4)));

// ---------------------------------------------------------------------------
// Kernel 1: transpose features (B,C,N) -> (B,N,C) into ws. sc0 sc1 stores
// write through to the coherence point (per-XCD L2s aren't cross-coherent and
// graph replay doesn't re-clean them — proven r2..r12).
// ---------------------------------------------------------------------------
__global__ __launch_bounds__(256) void transpose_feat(const float* __restrict__ f,
                                                      float* __restrict__ ft) {
    __shared__ float tile[64 * 65];
    const int b  = blockIdx.x >> 8;           // N/64 = 256 blocks per batch
    const int n0 = (blockIdx.x & 255) * 64;
    const int t  = threadIdx.x;
    const int nl = t & 63;
    const int cl = t >> 6;
    const float* fb = f + (size_t)b * C * N;
#pragma unroll
    for (int i = 0; i < 16; ++i) {
        const int c = i * 4 + cl;
        tile[c * 65 + nl] = fb[(size_t)c * N + n0 + nl];   // 256B coalesced per c
    }
    __syncthreads();
    float* ftb = ft + ((size_t)b * N + n0) * C;
    const int l15 = t & 15;
    const int nw  = t >> 4;                    // 0..15
#pragma unroll
    for (int it = 0; it < 4; ++it) {
        const int n = it * 16 + nw;
        f32x4 v;
#pragma unroll
        for (int k = 0; k < 4; ++k) v[k] = tile[(4 * l15 + k) * 65 + n];
        float* p = ftb + (size_t)n * C + 4 * l15;
        asm volatile("global_store_dwordx4 %0, %1, off sc0 sc1"
                     :: "v"(p), "v"(v) : "memory");
    }
}

// ---------------------------------------------------------------------------
// Kernel 2 "sg": fused scan+gather, one wave per query, 2 waves per block,
// per-wave LDS, no __syncthreads. r10 structure; scan now processes 256
// points per iteration (4 sub-chunks) with a 12-load batched prefetch —
// one L2-latency exposure per 256 points instead of per 64 (r12 post-mortem:
// scan latency, not the gather path, is the dominant cost).
// ---------------------------------------------------------------------------
__global__ __launch_bounds__(128, 8) void sg(const float* __restrict__ q_xyz,
                                             const float* __restrict__ s_xyz,
                                             const float* __restrict__ ft,
                                             float* __restrict__ out) {
    __shared__ int   idx_s[2][S];
    __shared__ float tile[2][16 * TS];

    const int t    = threadIdx.x;
    const int lane = t & 63;
    const int wid  = t >> 6;                 // 0..1
    const int gq   = blockIdx.x * 2 + wid;   // 0..B*Q-1
    const int b    = gq >> 12;               // Q = 4096
    const int q    = gq & (Q - 1);

    const float* qp = q_xyz + (size_t)gq * 3;
    const float qxf = qp[0], qyf = qp[1], qzf = qp[2];
    const double qxd = (double)qxf, qyd = (double)qyf, qzd = (double)qzf;
    const double R2D = 0.2 * 0.2;   // IEEE double = python's radius*radius
    const float R2F = 0.04f, EPS = 4e-6f;
    const float* sb = s_xyz + (size_t)b * N * 3;

    // ---- phase 1: ordered ballot ball-query, 4-deep pipelined ----
    float cx[4], cy[4], cz[4];
#pragma unroll
    for (int j = 0; j < 4; ++j) {            // preload chunks 0..3
        const int n = (j * 64 + lane) * 3;
        cx[j] = sb[n + 0]; cy[j] = sb[n + 1]; cz[j] = sb[n + 2];
    }
    int cnt = 0;                                            // wave-uniform
    for (int base = 0; base < N && cnt < S; base += 256) {
        float nx[4], ny[4], nz[4];
        if (base + 256 < N) {                // batched prefetch: 12 loads in flight
#pragma unroll
            for (int j = 0; j < 4; ++j) {
                const int n = (base + 256 + j * 64 + lane) * 3;
                nx[j] = sb[n + 0]; ny[j] = sb[n + 1]; nz[j] = sb[n + 2];
            }
        }
#pragma unroll
        for (int j = 0; j < 4; ++j) {        // ascending order preserved
            const float dxf = cx[j] - qxf, dyf = cy[j] - qyf, dzf = cz[j] - qzf;
            const float d2f = dxf * dxf + dyf * dyf + dzf * dzf;
            bool in = d2f < R2F - EPS;                       // definitely inside
            const bool border = (!in) && (d2f <= R2F + EPS); // needs exact decision
            if (__any(border)) {
                if (border) {
                    const double dx = (double)cx[j] - qxd;
                    const double dy = (double)cy[j] - qyd;
                    const double dz = (double)cz[j] - qzd;
                    in = (dx * dx + dy * dy + dz * dz) < R2D;   // exact f64 (proven)
                }
            }
            const unsigned long long m = __ballot(in);
            if (in) {
                const int pos = cnt + __popcll(m & ((1ull << lane) - 1ull));
                if (pos < S) idx_s[wid][pos] = base + j * 64 + lane;
            }
            cnt += __popcll(m);              // running cnt: ordering exact
        }
#pragma unroll
        for (int j = 0; j < 4; ++j) { cx[j] = nx[j]; cy[j] = ny[j]; cz[j] = nz[j]; }
    }
    if (cnt > S) cnt = S;
    const int idx0 = (cnt > 0) ? idx_s[wid][0] : 0;
    if (lane < S && lane >= cnt) idx_s[wid][lane] = idx0;  // pad (same wave)

    // ---- phase 2: gather + write (r10-proven, unchanged) ----
    const int sub = lane >> 4;           // 0..3 : row-within-quad for gather
    const int c15 = lane & 15;
    const int cq  = c15 * 4;             // col start (floats) for gather
    const int a4  = lane & 3;            // s-quad within pass for output
    const int ch  = lane >> 2;           // 0..15 : c within 16-c group for output
    float* out1 = out + (size_t)B * 3 * Q * S;
    const float* ftb = ft + (size_t)b * N * C;

    // issue all 8 gather loads up-front (L3-coherent, bypass stale L2) G0..G7
    f32x4 v[8];
#pragma unroll
    for (int j = 0; j < 8; ++j) {
        const int id = idx_s[wid][j * 4 + sub];
        const float* p = ftb + ((size_t)id << 6) + cq;
        asm volatile("global_load_dwordx4 %0, %1, off sc0 sc1"
                     : "=v"(v[j]) : "v"(p));
    }

    // grouped_xyz overlaps gather latency: 2 counted asm stores S0,S1
    {
        const int c0 = lane >> 5, s0 = lane & 31;
        const int id0 = idx_s[wid][s0];
        const float w0 = sb[id0 * 3 + c0] - qp[c0];
        float* p0 = out + (((size_t)b * 3 + c0) * Q + q) * S + s0;
        asm volatile("global_store_dword %0, %1, off" :: "v"(p0), "v"(w0) : "memory");
        float w1 = 0.0f;
        float* p1 = p0;
        if (lane < 32) {
            const int id1 = idx_s[wid][lane];
            w1 = sb[id1 * 3 + 2] - qp[2];
            p1 = out + (((size_t)b * 3 + 2) * Q + q) * S + lane;
        }
        if (lane < 32)
            asm volatile("global_store_dword %0, %1, off" :: "v"(p1), "v"(w1) : "memory");
    }

    // ---- pass 0: s = 0..15 ----
    // >=6 ops younger than G3 (G4..G7,S0,S1) => vmcnt(6) proves G0..G3 done.
    asm volatile("s_waitcnt vmcnt(6)" ::: "memory");
    __builtin_amdgcn_sched_barrier(0);
#pragma unroll
    for (int j = 0; j < 4; ++j) {
        const int r = j * 4 + sub;
        *(f32x4*)&tile[wid][r * TS + cq] = v[j];
    }
#pragma unroll
    for (int i = 0; i < 4; ++i) {        // O0..O3: c = 16i+ch, s quad a4
        const int c = i * 16 + ch;
        f32x4 w;
#pragma unroll
        for (int k = 0; k < 4; ++k)
            w[k] = tile[wid][(4 * a4 + k) * TS + c];
        float* p = out1 + (((size_t)b * C + c) * Q + q) * S + 4 * a4;
        asm volatile("global_store_dwordx4 %0, %1, off" :: "v"(p), "v"(w) : "memory");
    }

    // ---- pass 1: s = 16..31 ----
    // >=4 ops younger than G7 (O0..O3) => vmcnt(4) proves G4..G7 done.
    asm volatile("s_waitcnt vmcnt(4)" ::: "memory");
    __builtin_amdgcn_sched_barrier(0);
#pragma unroll
    for (int j = 0; j < 4; ++j) {
        const int r = j * 4 + sub;
        *(f32x4*)&tile[wid][r * TS + cq] = v[4 + j];
    }
#pragma unroll
    for (int i = 0; i < 4; ++i) {
        const int c = i * 16 + ch;
        f32x4 w;
#pragma unroll
        for (int k = 0; k < 4; ++k)
            w[k] = tile[wid][(4 * a4 + k) * TS + c];
        float* p = out1 + (((size_t)b * C + c) * Q + q) * S + 16 + 4 * a4;
        asm volatile("global_store_dwordx4 %0, %1, off" :: "v"(p), "v"(w) : "memory");
    }
}

// ---------------------------------------------------------------------------
// Fallback (ws too small): fused single kernel, original feature layout.
// ---------------------------------------------------------------------------
__global__ __launch_bounds__(256) void ballgroup_fb(const float* __restrict__ q_xyz,
                                                    const float* __restrict__ s_xyz,
                                                    const float* __restrict__ feat,
                                                    float* __restrict__ out) {
    __shared__ int   idx_s[4][S];
    __shared__ float tile[4][16 * TS];
    const int t = threadIdx.x, lane = t & 63, wid = t >> 6;
    const int gq = blockIdx.x * 4 + wid;
    const int b = gq >> 12, q = gq & (Q - 1);
    const float* qp = q_xyz + (size_t)gq * 3;
    const double qxd = (double)qp[0], qyd = (double)qp[1], qzd = (double)qp[2];
    const double R2D = 0.2 * 0.2;
    const float* sb = s_xyz + (size_t)b * N * 3;
    int cnt = 0;
    for (int base = 0; base < N && cnt < S; base += 64) {
        const int n = base + lane;
        const double dx = (double)sb[n * 3 + 0] - qxd;
        const double dy = (double)sb[n * 3 + 1] - qyd;
        const double dz = (double)sb[n * 3 + 2] - qzd;
        const bool in = (dx * dx + dy * dy + dz * dz) < R2D;
        const unsigned long long m = __ballot(in);
        if (in) {
            const int pos = cnt + __popcll(m & ((1ull << lane) - 1ull));
            if (pos < S) idx_s[wid][pos] = n;
        }
        cnt += __popcll(m);
    }
    if (cnt > S) cnt = S;
    const int idx0 = (cnt > 0) ? idx_s[wid][0] : 0;
    if (lane < S && lane >= cnt) idx_s[wid][lane] = idx0;
    for (int e = lane; e < 3 * S; e += 64) {
        const int c = e >> 5, sI = e & 31;
        const int id = idx_s[wid][sI];
        out[(((size_t)b * 3 + c) * Q + q) * S + sI] = sb[id * 3 + c] - qp[c];
    }
    float* out1 = out + (size_t)B * 3 * Q * S;
    const int chi = lane >> 4, sI16 = lane & 15;
    const float* fb = feat + (size_t)b * C * N;
    for (int p = 0; p < 2; ++p) {
        for (int s2 = 0; s2 < 16; ++s2) {
            const int id = idx_s[wid][p * 16 + s2];
            tile[wid][s2 * TS + lane] = fb[(size_t)lane * N + id];
        }
#pragma unroll
        for (int i = 0; i < 16; ++i) {
            const int c = i * 4 + chi;
            out1[(((size_t)b * C + c) * Q + q) * S + p * 16 + sI16] =
                tile[wid][sI16 * TS + c];
        }
    }
}

extern "C" void kernel_launch(void* const* d_in, const int* in_sizes, int n_in,
                              void* d_out, int out_size, void* d_ws, size_t ws_size,
                              hipStream_t stream) {
    const float* q_xyz = (const float*)d_in[0];   // (B,Q,3)
    const float* s_xyz = (const float*)d_in[1];   // (B,N,3)
    const float* feat  = (const float*)d_in[2];   // (B,C,N)
    float* out = (float*)d_out;

    const size_t ftBytes = (size_t)B * N * C * sizeof(float);   // 16 MB
    if (ws_size >= ftBytes) {
        float* ft = (float*)d_ws;
        transpose_feat<<<B * (N / 64), 256, 0, stream>>>(feat, ft);
        sg<<<QBLKS, 128, 0, stream>>>(q_xyz, s_xyz, ft, out);
    } else {
        ballgroup_fb<<<(B * Q) / 4, 256, 0, stream>>>(q_xyz, s_xyz, feat, out);
    }
}